// Round 18
// baseline (136.593 us; speedup 1.0000x reference)
//
#include <hip/hip_runtime.h>

typedef __attribute__((ext_vector_type(8))) short bfrag8;    // 8 bf16 (4 VGPRs)
typedef __attribute__((ext_vector_type(4))) short bfrag4;    // 4 bf16 (2 VGPRs)
typedef __attribute__((ext_vector_type(16))) float f32x16;   // 32x32 MFMA acc

#define B_ 16
#define C_ 64
#define H_ 128
#define W_ 128
#define E_ 4
#define HW_ (H_ * W_)

// ring geometry: 64-px half-rows, 66 slots (px-1..64 rel), 8 ci-chunks of 8
#define NSL 66
#define PLANE2 (NSL * 16)       // 1056 B
#define ROWB2  (8 * PLANE2)     // 8448 B
#define RG 8                    // output rows per block, 2 per step (4 steps)
#define NRS 6                   // ring slots

// ---- fast-path ws layout (bytes) ----
// wT2: bf16 MFMA A-fragment layout [e][tap][ch][kb][lane64][8]
#define WT_ELEMS (4 * 9 * 2 * 4 * 64 * 8)      // 147,456 bf16
#define OFF_POOL (WT_ELEMS * 2)
#define OFF_EW   (OFF_POOL + 1024 * 4)
#define WS_NEEDED ((size_t)(OFF_EW + 64 * 4))

// ---- fallback ws layout (floats) ----
#define FB_WT_OFF 0
#define FB_POOLED_OFF 147456
#define FB_EW_OFF 148480

__device__ inline unsigned short f2bf(float f) {
    unsigned u = __builtin_bit_cast(unsigned, f);
    unsigned r = u + 0x7FFFu + ((u >> 16) & 1u);
    return (unsigned short)(r >> 16);
}
__device__ inline float bf2f(unsigned short s) {
    return __builtin_bit_cast(float, (unsigned)s << 16);
}

// ---------------- pool (per (b,c) block) + fused weight convert to frag layout ----------------
__global__ __launch_bounds__(256) void pool_wcvt(const float* __restrict__ in,
                                                 const float* __restrict__ cw,
                                                 float* __restrict__ pooled,
                                                 unsigned short* __restrict__ wT2) {
    if (blockIdx.x < 576) {
        const int idx = blockIdx.x * 256 + threadIdx.x;   // 0..147455
        const int j = idx & 7;
        const int l = (idx >> 3) & 63;
        const int f = idx >> 9;          // frag 0..287 = ((e*9+tap)*2+ch)*4+kb
        const int kb = f & 3;
        const int chh = (f >> 2) & 1;
        const int et = f >> 3;
        const int tap = et % 9;
        const int e = et / 9;
        const int co = chh * 32 + (l & 31);
        const int ci = kb * 16 + (l >> 5) * 8 + j;
        wT2[idx] = f2bf(cw[(((e * C_ + co) * C_ + ci) * 9) + tap]);
    }
    const int bc = blockIdx.x;
    const float* p = in + (size_t)bc * HW_;
    float s = 0.f;
    for (int i = threadIdx.x; i < HW_ / 4; i += 256) {
        float4 v = ((const float4*)p)[i];
        s += v.x + v.y + v.z + v.w;
    }
    for (int off = 32; off; off >>= 1) s += __shfl_down(s, off);
    __shared__ float red[4];
    const int lane = threadIdx.x & 63, wv = threadIdx.x >> 6;
    if (lane == 0) red[wv] = s;
    __syncthreads();
    if (threadIdx.x == 0)
        pooled[bc] = (red[0] + red[1] + red[2] + red[3]) * (1.0f / (float)HW_);
}

// ---------------- gate (fallback path only; fast path folds gate into conv) ----------------
__global__ void gate_kernel(const float* __restrict__ pooled,
                            const float* __restrict__ gate_w,
                            const float* __restrict__ gate_b,
                            float* __restrict__ ew) {
    const int b = threadIdx.x;
    if (b >= B_) return;
    float lg[E_];
    for (int e = 0; e < E_; e++) {
        float s = gate_b[e];
        for (int c = 0; c < C_; c++) s += pooled[b * C_ + c] * gate_w[e * C_ + c];
        lg[e] = s;
    }
    float m = fmaxf(fmaxf(lg[0], lg[1]), fmaxf(lg[2], lg[3]));
    float ex[E_], sum = 0.f;
    for (int e = 0; e < E_; e++) { ex[e] = expf(lg[e] - m); sum += ex[e]; }
    for (int e = 0; e < E_; e++) ex[e] /= sum;
    int i1 = 0;
    for (int e = 1; e < E_; e++) if (ex[e] > ex[i1]) i1 = e;
    int i2 = -1;
    for (int e = 0; e < E_; e++) {
        if (e == i1) continue;
        if (i2 < 0 || ex[e] > ex[i2]) i2 = e;
    }
    for (int e = 0; e < E_; e++)
        ew[b * E_ + e] = (e == i1 || e == i2) ? ex[e] : 0.f;
}

// ---------------- conv: A-reuse x2 AND B-reuse x2, 4 accs/wave ----------------
// 512 blocks = img(16) x pxhalf(2) x rowgroup(16 x RG=8 rows); 3 blocks/CU
// (LDS 50.7 KB). 256 thr, 4 waves = rh(2: row parity) x ch(2: co half).
// Wave tile: 1 row x 32co x 64px x 2 experts = 4 accs. Each A-fragment feeds
// 2 px-quarters (A L2 traffic 1.2GB -> 600MB) and each ds_read_b128 feeds 2
// experts (LDS reads 590K -> 295K) — the two largest serial-sum terms.
// unroll-1 on ky/kx/kb keeps in-flight regs small (r15 lesson). float4
// staging: 8x16B loads/thread instead of 32 scalar. (256,1): demand ~150.
__global__ __launch_bounds__(256, 1) void conv_4a(const float* __restrict__ in,
                                                  const float* __restrict__ kk,
                                                  const float* __restrict__ cb,
                                                  const float* __restrict__ pooled,
                                                  const float* __restrict__ gw,
                                                  const float* __restrict__ gb,
                                                  const unsigned short* __restrict__ wT2,
                                                  float* __restrict__ out) {
    const int raw = blockIdx.x;                     // 512 blocks
    const int swz = (raw & 7) * 64 + (raw >> 3);    // XCD-bijective (512 % 8 == 0)
    const int b   = swz >> 5;                       // 32 blocks per image
    const int pxh = (swz >> 4) & 1;
    const int h0  = (swz & 15) * RG;
    const int x0g = pxh * 64;

    const int tid = threadIdx.x;
    const int lane = tid & 63;
    const int wv = tid >> 6;          // 0..3
    const int ln = lane & 31;
    const int lh = lane >> 5;
    const int rh = wv >> 1;           // row parity within the step pair
    const int ch = wv & 1;            // co half
    const int co0 = ch * 32;

    // staging roles: thread covers 4 px x 8 ci of one row
    const int sq   = tid & 15;        // px quad (px = sq*4 .. +3)
    const int sc   = (tid >> 4) & 7;  // ci oct (ci = sc*8 .. +7)
    const int srow = tid >> 7;        // row parity

    __shared__ __align__(16) char ring[NRS * ROWB2];   // 50,688 B
    __shared__ float sEW[E_];

    // ---- gate (wave 0 recomputes; broadcast via LDS) ----
    if (tid < 64) {
        const float p = pooled[b * C_ + lane];
        float part[E_];
#pragma unroll
        for (int e = 0; e < E_; e++) part[e] = p * gw[e * C_ + lane];
#pragma unroll
        for (int off = 32; off; off >>= 1)
#pragma unroll
            for (int e = 0; e < E_; e++) part[e] += __shfl_down(part[e], off);
        if (lane == 0) {
            float lg[E_];
#pragma unroll
            for (int e = 0; e < E_; e++) lg[e] = part[e] + gb[e];
            float m = fmaxf(fmaxf(lg[0], lg[1]), fmaxf(lg[2], lg[3]));
            float ex[E_], sum = 0.f;
#pragma unroll
            for (int e = 0; e < E_; e++) { ex[e] = __expf(lg[e] - m); sum += ex[e]; }
            const float inv = 1.0f / sum;
            int i1 = 0;
            for (int e = 1; e < E_; e++) if (ex[e] > ex[i1]) i1 = e;
            int i2 = -1;
            for (int e = 0; e < E_; e++) {
                if (e == i1) continue;
                if (i2 < 0 || ex[e] > ex[i2]) i2 = e;
            }
#pragma unroll
            for (int e = 0; e < E_; e++)
                sEW[e] = (e == i1 || e == i2) ? ex[e] * inv : 0.f;
        }
    }
    __syncthreads();

    int e0 = 0, e1 = 0; float w0 = 0.f, w1 = 0.f;
    {
        int found = 0;
        for (int e = 0; e < E_; e++) {
            float we = sEW[e];
            if (we != 0.f) {
                if (!found) { e0 = e; w0 = we; found = 1; }
                else        { e1 = e; w1 = we; }
            }
        }
        if (w1 == 0.f) e1 = e0;   // degenerate: w1=0 zeroes its contribution
    }

    const float* cb0 = cb + e0 * C_;
    const float* cb1 = cb + e1 * C_;
    const float* kkp = kk + b * C_;

    float4 pv4[8];                    // 4 px x 8 ci of one row
    float ph[8];                      // halo (tid<32)
    // STAGE(pr): stage rows pr+srow
    auto STAGE = [&](int pr) {
        const int r = pr + srow;
        if ((unsigned)r < (unsigned)H_) {
            const float* src = in + ((size_t)(b * C_ + sc * 8) * H_ + r) * W_ + x0g + sq * 4;
#pragma unroll
            for (int i = 0; i < 8; ++i)
                pv4[i] = *(const float4*)(src + (size_t)i * HW_);
        } else {
            const float4 z = make_float4(0.f, 0.f, 0.f, 0.f);
#pragma unroll
            for (int i = 0; i < 8; ++i) pv4[i] = z;
        }
        if (tid < 32) {
            const int hp = tid & 1;
            const int cgh = (tid >> 1) & 7;
            const int hrow = tid >> 4;           // 0/1
            const int rr = pr + hrow;
            const int pg = hp ? (x0g + 64) : (x0g - 1);
            const bool ok = ((unsigned)rr < (unsigned)H_) && ((unsigned)pg < (unsigned)W_);
            const float* src = in + ((size_t)(b * C_ + cgh * 8) * H_ + (((unsigned)rr < (unsigned)H_) ? rr : 0)) * W_ + (ok ? pg : 0);
#pragma unroll
            for (int i = 0; i < 8; ++i) ph[i] = ok ? src[(size_t)i * HW_] : 0.f;
        }
    };
    // COMMIT(sl0): rows land in slots sl0+srow (mod 6)
    auto COMMIT = [&](int sl0) {
        int sl = sl0 + srow; if (sl >= NRS) sl -= NRS;
        char* bp = ring + sl * ROWB2 + sc * PLANE2;
#pragma unroll
        for (int p = 0; p < 4; ++p) {
            bfrag8 f;
            f[0] = (short)f2bf(pv4[0][p]); f[1] = (short)f2bf(pv4[1][p]);
            f[2] = (short)f2bf(pv4[2][p]); f[3] = (short)f2bf(pv4[3][p]);
            f[4] = (short)f2bf(pv4[4][p]); f[5] = (short)f2bf(pv4[5][p]);
            f[6] = (short)f2bf(pv4[6][p]); f[7] = (short)f2bf(pv4[7][p]);
            *(bfrag8*)(bp + (sq * 4 + p + 1) * 16) = f;
        }
        if (tid < 32) {
            const int hp = tid & 1;
            const int cgh = (tid >> 1) & 7;
            const int hrow = tid >> 4;
            int slh = sl0 + hrow; if (slh >= NRS) slh -= NRS;
            bfrag8 g;
#pragma unroll
            for (int i = 0; i < 8; ++i) g[i] = (short)f2bf(ph[i]);
            *(bfrag8*)(ring + slh * ROWB2 + cgh * PLANE2 + (hp ? 65 : 0) * 16) = g;
        }
    };

    // prologue: rows h0-1..h0+2 -> locals 0..3  (local(r) = r - h0 + 1)
    STAGE(h0 - 1); COMMIT(0);
    STAGE(h0 + 1); COMMIT(2);
    __syncthreads();

    const char* wb0 = (const char*)wT2 + (size_t)e0 * 73728 + ch * 4096 + lane * 16;
    const char* wb1 = (const char*)wT2 + (size_t)e1 * 73728 + ch * 4096 + lane * 16;

    for (int t = 0; t < RG / 2; ++t) {
        if (t + 1 < RG / 2) STAGE(h0 + 2 * t + 3);   // rows +3,+4 in flight over MFMA

        const int myloc = 2 * t + rh;                // local of this wave's row

        f32x16 A00, A01, A10, A11;   // (e0,q0)(e0,q1)(e1,q0)(e1,q1): 32co x 32px each
#pragma unroll
        for (int i = 0; i < 16; ++i) { A00[i] = 0.f; A01[i] = 0.f; A10[i] = 0.f; A11[i] = 0.f; }

#pragma unroll 1
        for (int ky = 0; ky < 3; ++ky) {
            int u = myloc + ky; if (u >= NRS) u -= NRS;
            const char* rb = ring + u * ROWB2;
            const char* wk0 = wb0 + ky * 24576;
            const char* wk1 = wb1 + ky * 24576;
#pragma unroll 1
            for (int kx = 0; kx < 3; ++kx) {
#pragma unroll 1
                for (int kb = 0; kb < 4; ++kb) {
                    bfrag8 a0 = *(const bfrag8*)(wk0 + kx * 8192 + kb * 1024);
                    bfrag8 a1 = *(const bfrag8*)(wk1 + kx * 8192 + kb * 1024);
                    const char* bp = rb + (kb * 2 + lh) * PLANE2 + (ln + kx) * 16;
                    bfrag8 b0 = *(const bfrag8*)(bp);
                    bfrag8 b1 = *(const bfrag8*)(bp + 512);   // +32 slots
                    A00 = __builtin_amdgcn_mfma_f32_32x32x16_bf16(a0, b0, A00, 0, 0, 0);
                    A01 = __builtin_amdgcn_mfma_f32_32x32x16_bf16(a0, b1, A01, 0, 0, 0);
                    A10 = __builtin_amdgcn_mfma_f32_32x32x16_bf16(a1, b0, A10, 0, 0, 0);
                    A11 = __builtin_amdgcn_mfma_f32_32x32x16_bf16(a1, b1, A11, 0, 0, 0);
                }
            }
        }

        // commit rows h0+2t+3/+4 into locals (2t+4)%6,(2t+5)%6 (unread this step)
        if (t + 1 < RG / 2) {
            int sl0 = 2 * t + 4; if (sl0 >= NRS) sl0 -= NRS;
            COMMIT(sl0);
        }

        // epilogue: out = resid(bf16, local myloc+1) + relu(a+b)*k*w (both experts)
        const int row = h0 + 2 * t + rh;
        int v = myloc + 1; if (v >= NRS) v -= NRS;
        const char* rm1 = ring + v * ROWB2 + lh * 8;
        bfrag4 ra0[4], ra1[4];
#pragma unroll
        for (int c = 0; c < 4; ++c) {
            ra0[c] = *(const bfrag4*)(rm1 + (ch * 4 + c) * PLANE2 + (ln + 1) * 16);
            ra1[c] = *(const bfrag4*)(rm1 + (ch * 4 + c) * PLANE2 + (ln + 33) * 16);
        }
#pragma unroll
        for (int g = 0; g < 16; ++g) {
            const int r_ = g & 3, c_ = g >> 2;
            const int co = co0 + r_ + 8 * c_ + 4 * lh;
            const float kv = kkp[co];
            const float f0 = kv * w0, f1 = kv * w1;
            const float b0v = cb0[co], b1v = cb1[co];
            const size_t base = ((size_t)(b * C_ + co) * H_ + row) * W_ + x0g;
            out[base + ln]      = bf2f((unsigned short)ra0[c_][r_])
                                  + fmaxf(A00[g] + b0v, 0.f) * f0
                                  + fmaxf(A10[g] + b1v, 0.f) * f1;
            out[base + 32 + ln] = bf2f((unsigned short)ra1[c_][r_])
                                  + fmaxf(A01[g] + b0v, 0.f) * f0
                                  + fmaxf(A11[g] + b1v, 0.f) * f1;
        }

        __syncthreads();   // single barrier: commits visible; next step's overwrites safe
    }
}

// ================= fallback (fp32 path, used only if ws too small) =================
#define CHUNK 32

__global__ __launch_bounds__(256) void pool_kernel(const float* __restrict__ in,
                                                   float* __restrict__ pooled) {
    const int bc = blockIdx.x;
    const float* p = in + (size_t)bc * HW_;
    float s = 0.f;
    for (int i = threadIdx.x; i < HW_ / 4; i += 256) {
        float4 v = ((const float4*)p)[i];
        s += v.x + v.y + v.z + v.w;
    }
    for (int off = 32; off; off >>= 1) s += __shfl_down(s, off);
    __shared__ float red[4];
    const int lane = threadIdx.x & 63, wv = threadIdx.x >> 6;
    if (lane == 0) red[wv] = s;
    __syncthreads();
    if (threadIdx.x == 0)
        pooled[bc] = (red[0] + red[1] + red[2] + red[3]) * (1.0f / (float)HW_);
}

__global__ __launch_bounds__(256) void wtr_kernel(const float* __restrict__ cw,
                                                  float* __restrict__ wT) {
    const int idx = blockIdx.x * 256 + threadIdx.x;
    if (idx >= E_ * C_ * 9 * C_) return;
    const int co = idx & 63;
    const int t2 = idx >> 6;
    const int tap = t2 % 9;
    const int t3 = t2 / 9;
    const int ci = t3 & 63;
    const int e = t3 >> 6;
    wT[idx] = cw[(((e * C_ + co) * C_ + ci) * 9) + tap];
}

__global__ __launch_bounds__(512) void conv_fallback(const float* __restrict__ in,
                                                     const float* __restrict__ kk,
                                                     const float* __restrict__ wT,
                                                     const float* __restrict__ cb,
                                                     const float* __restrict__ ew,
                                                     float* __restrict__ out) {
    const int bid = blockIdx.x;
    const int b = bid / H_;
    const int h = bid % H_;
    const int tid = threadIdx.x;
    const int lane = tid & 63;
    const int wv = tid >> 6;
    const int x0 = wv * 16;

    __shared__ float sIn[CHUNK * 3 * W_];

    float w0 = 0.f, w1 = 0.f;
    int e0 = 0, e1 = 0;
    {
        float we[E_];
#pragma unroll
        for (int e = 0; e < E_; e++) we[e] = ew[b * E_ + e];
        int found = 0;
        for (int e = 0; e < E_; e++) {
            if (we[e] != 0.f) {
                if (!found) { e0 = e; w0 = we[e]; found = 1; }
                else        { e1 = e; w1 = we[e]; }
            }
        }
        if (w1 == 0.f) e1 = e0;
    }

    float acc0[16], acc1[16];
#pragma unroll
    for (int i = 0; i < 16; i++) { acc0[i] = 0.f; acc1[i] = 0.f; }

    for (int cblk = 0; cblk < C_ / CHUNK; cblk++) {
        const int cbase = cblk * CHUNK;
        __syncthreads();
        for (int f = tid; f < CHUNK * 3 * W_ / 4; f += 512) {
            const int fi = f * 4;
            const int ci = fi / (3 * W_);
            const int rem = fi - ci * 3 * W_;
            const int kyy = rem / W_;
            const int x = rem - kyy * W_;
            const int hh = h + kyy - 1;
            float4 v = make_float4(0.f, 0.f, 0.f, 0.f);
            if (hh >= 0 && hh < H_)
                v = *(const float4*)(in + ((size_t)(b * C_ + cbase + ci) * H_ + hh) * W_ + x);
            *(float4*)(sIn + fi) = v;
        }
        __syncthreads();

        const float* wp0 = wT + (size_t)((e0 * C_ + cbase) * 9) * C_ + lane;
        const float* wp1 = wT + (size_t)((e1 * C_ + cbase) * 9) * C_ + lane;
        for (int ci = 0; ci < CHUNK; ci++) {
            float wa[9], wb[9];
#pragma unroll
            for (int t = 0; t < 9; t++) {
                wa[t] = wp0[(ci * 9 + t) * C_];
                wb[t] = wp1[(ci * 9 + t) * C_];
            }
            const float* rowp = sIn + ci * 3 * W_;
#pragma unroll
            for (int kyy = 0; kyy < 3; kyy++) {
                float xin[18];
                const float* rp = rowp + kyy * W_ + x0;
                xin[0] = (x0 == 0) ? 0.f : rp[-1];
#pragma unroll
                for (int j = 0; j < 16; j += 4) {
                    float4 v = *(const float4*)(rp + j);
                    xin[1 + j] = v.x; xin[2 + j] = v.y; xin[3 + j] = v.z; xin[4 + j] = v.w;
                }
                xin[17] = (x0 + 16 >= W_) ? 0.f : rp[16];
                const int t0 = kyy * 3;
#pragma unroll
                for (int x = 0; x < 16; x++) {
                    acc0[x] += xin[x] * wa[t0] + xin[x + 1] * wa[t0 + 1] + xin[x + 2] * wa[t0 + 2];
                    acc1[x] += xin[x] * wb[t0] + xin[x + 1] * wb[t0 + 1] + xin[x + 2] * wb[t0 + 2];
                }
            }
        }
    }

    const float kv = kk[b * C_ + lane];
    const float b0v = cb[e0 * C_ + lane];
    const float b1v = cb[e1 * C_ + lane];
    const float kw0 = kv * w0, kw1 = kv * w1;
    const size_t obase = ((size_t)(b * C_ + lane) * H_ + h) * W_ + x0;
#pragma unroll
    for (int x = 0; x < 16; x += 4) {
        float4 iv = *(const float4*)(in + obase + x);
        float4 ov;
        ov.x = iv.x + fmaxf(acc0[x + 0] + b0v, 0.f) * kw0 + fmaxf(acc1[x + 0] + b1v, 0.f) * kw1;
        ov.y = iv.y + fmaxf(acc0[x + 1] + b0v, 0.f) * kw0 + fmaxf(acc1[x + 1] + b1v, 0.f) * kw1;
        ov.z = iv.z + fmaxf(acc0[x + 2] + b0v, 0.f) * kw0 + fmaxf(acc1[x + 2] + b1v, 0.f) * kw1;
        ov.w = iv.w + fmaxf(acc0[x + 3] + b0v, 0.f) * kw0 + fmaxf(acc1[x + 3] + b1v, 0.f) * kw1;
        *(float4*)(out + obase + x) = ov;
    }
}

extern "C" void kernel_launch(void* const* d_in, const int* in_sizes, int n_in,
                              void* d_out, int out_size, void* d_ws, size_t ws_size,
                              hipStream_t stream) {
    const float* inputs = (const float*)d_in[0];
    const float* k      = (const float*)d_in[1];
    const float* gate_w = (const float*)d_in[2];
    const float* gate_b = (const float*)d_in[3];
    const float* conv_w = (const float*)d_in[4];
    const float* conv_b = (const float*)d_in[5];
    float* out = (float*)d_out;
    char* wsb = (char*)d_ws;

    if (ws_size >= WS_NEEDED) {
        unsigned short* wT2 = (unsigned short*)wsb;
        float* pooled = (float*)(wsb + OFF_POOL);

        pool_wcvt<<<B_ * C_, 256, 0, stream>>>(inputs, conv_w, pooled, wT2);
        conv_4a<<<512, 256, 0, stream>>>(inputs, k, conv_b, pooled,
                                         gate_w, gate_b, wT2, out);
    } else {
        float* ws = (float*)d_ws;
        float* wTf    = ws + FB_WT_OFF;
        float* pooled = ws + FB_POOLED_OFF;
        float* ewbuf  = ws + FB_EW_OFF;

        pool_kernel<<<B_ * C_, 256, 0, stream>>>(inputs, pooled);
        gate_kernel<<<1, 64, 0, stream>>>(pooled, gate_w, gate_b, ewbuf);
        wtr_kernel<<<(E_ * C_ * 9 * C_ + 255) / 256, 256, 0, stream>>>(conv_w, wTf);
        conv_fallback<<<B_ * H_, 512, 0, stream>>>(inputs, k, wTf, conv_b, ewbuf, out);
    }
}

// Round 19
// 90.053 us; speedup vs baseline: 1.5168x; 1.5168x over previous
//
#include <hip/hip_runtime.h>

typedef __attribute__((ext_vector_type(8))) short bfrag8;    // 8 bf16 (4 VGPRs)
typedef __attribute__((ext_vector_type(4))) short bfrag4;    // 4 bf16 (2 VGPRs)
typedef __attribute__((ext_vector_type(16))) float f32x16;   // 32x32 MFMA acc

#define B_ 16
#define C_ 64
#define H_ 128
#define W_ 128
#define E_ 4
#define HW_ (H_ * W_)

// ring geometry: 64-px half-rows, 66 slots (px-1..64 rel), 8 ci-chunks of 8
#define NSL 66
#define PLANE2 (NSL * 16)       // 1056 B
#define ROWB2  (8 * PLANE2)     // 8448 B
#define RG 8                    // output rows per block, 2 per step (4 steps)
#define NRS 6                   // ring slots

// ---- fast-path ws layout (bytes) ----
// wT2: bf16 MFMA A-fragment layout [e][tap][ch][kb][lane64][8]
#define WT_ELEMS (4 * 9 * 2 * 4 * 64 * 8)      // 147,456 bf16
#define OFF_POOL (WT_ELEMS * 2)
#define OFF_EW   (OFF_POOL + 1024 * 4)
#define WS_NEEDED ((size_t)(OFF_EW + 64 * 4))

// ---- fallback ws layout (floats) ----
#define FB_WT_OFF 0
#define FB_POOLED_OFF 147456
#define FB_EW_OFF 148480

__device__ inline unsigned short f2bf(float f) {
    unsigned u = __builtin_bit_cast(unsigned, f);
    unsigned r = u + 0x7FFFu + ((u >> 16) & 1u);
    return (unsigned short)(r >> 16);
}
__device__ inline float bf2f(unsigned short s) {
    return __builtin_bit_cast(float, (unsigned)s << 16);
}

// ---------------- pool (per (b,c) block) + fused weight convert to frag layout ----------------
__global__ __launch_bounds__(256) void pool_wcvt(const float* __restrict__ in,
                                                 const float* __restrict__ cw,
                                                 float* __restrict__ pooled,
                                                 unsigned short* __restrict__ wT2) {
    if (blockIdx.x < 576) {
        const int idx = blockIdx.x * 256 + threadIdx.x;   // 0..147455
        const int j = idx & 7;
        const int l = (idx >> 3) & 63;
        const int f = idx >> 9;          // frag 0..287 = ((e*9+tap)*2+ch)*4+kb
        const int kb = f & 3;
        const int chh = (f >> 2) & 1;
        const int et = f >> 3;
        const int tap = et % 9;
        const int e = et / 9;
        const int co = chh * 32 + (l & 31);
        const int ci = kb * 16 + (l >> 5) * 8 + j;
        wT2[idx] = f2bf(cw[(((e * C_ + co) * C_ + ci) * 9) + tap]);
    }
    const int bc = blockIdx.x;
    const float* p = in + (size_t)bc * HW_;
    float s = 0.f;
    for (int i = threadIdx.x; i < HW_ / 4; i += 256) {
        float4 v = ((const float4*)p)[i];
        s += v.x + v.y + v.z + v.w;
    }
    for (int off = 32; off; off >>= 1) s += __shfl_down(s, off);
    __shared__ float red[4];
    const int lane = threadIdx.x & 63, wv = threadIdx.x >> 6;
    if (lane == 0) red[wv] = s;
    __syncthreads();
    if (threadIdx.x == 0)
        pooled[bc] = (red[0] + red[1] + red[2] + red[3]) * (1.0f / (float)HW_);
}

// ---------------- gate (fallback path only; fast path folds gate into conv) ----------------
__global__ void gate_kernel(const float* __restrict__ pooled,
                            const float* __restrict__ gate_w,
                            const float* __restrict__ gate_b,
                            float* __restrict__ ew) {
    const int b = threadIdx.x;
    if (b >= B_) return;
    float lg[E_];
    for (int e = 0; e < E_; e++) {
        float s = gate_b[e];
        for (int c = 0; c < C_; c++) s += pooled[b * C_ + c] * gate_w[e * C_ + c];
        lg[e] = s;
    }
    float m = fmaxf(fmaxf(lg[0], lg[1]), fmaxf(lg[2], lg[3]));
    float ex[E_], sum = 0.f;
    for (int e = 0; e < E_; e++) { ex[e] = expf(lg[e] - m); sum += ex[e]; }
    for (int e = 0; e < E_; e++) ex[e] /= sum;
    int i1 = 0;
    for (int e = 1; e < E_; e++) if (ex[e] > ex[i1]) i1 = e;
    int i2 = -1;
    for (int e = 0; e < E_; e++) {
        if (e == i1) continue;
        if (i2 < 0 || ex[e] > ex[i2]) i2 = e;
    }
    for (int e = 0; e < E_; e++)
        ew[b * E_ + e] = (e == i1 || e == i2) ? ex[e] : 0.f;
}

// ---------------- conv: A-reuse x2 + B-reuse x2 with PROVEN mechanics ----------------
// r18's tile (4 waves = rh(2) x ch(2); 1 row x 32co x 64px x 2 experts = 4 accs)
// with the two r18 bugs fixed:
//  (1) staging = r16/r17 pattern (thread: 16 ci x 1 px, both rows) ->
//      lanes write consecutive 16B in LDS, conflict-free;
//  (2) kb loop FULLY unrolled (unroll-1 only on ky/kx) -> compiler pipelines
//      the 8 A-frag + 8 B-frag loads against 16 MFMAs per kx (r14/r16 recipe).
// 512 blocks = img(16) x pxhalf(2) x rowgroup(16 x RG=8 rows); 6-slot ring,
// 2 rows/step, ONE barrier/step. A-side L2 traffic and LDS reads both halved
// vs r17 — the two largest serial-sum terms.
__global__ __launch_bounds__(256, 1) void conv_4b(const float* __restrict__ in,
                                                  const float* __restrict__ kk,
                                                  const float* __restrict__ cb,
                                                  const float* __restrict__ pooled,
                                                  const float* __restrict__ gw,
                                                  const float* __restrict__ gb,
                                                  const unsigned short* __restrict__ wT2,
                                                  float* __restrict__ out) {
    const int raw = blockIdx.x;                     // 512 blocks
    const int swz = (raw & 7) * 64 + (raw >> 3);    // XCD-bijective (512 % 8 == 0)
    const int b   = swz >> 5;                       // 32 blocks per image
    const int pxh = (swz >> 4) & 1;
    const int h0  = (swz & 15) * RG;
    const int x0g = pxh * 64;

    const int tid = threadIdx.x;
    const int lane = tid & 63;
    const int wv = tid >> 6;          // 0..3
    const int ln = lane & 31;
    const int lh = lane >> 5;
    const int rh = wv >> 1;           // row parity within the step pair
    const int ch = wv & 1;            // co half
    const int co0 = ch * 32;

    const int spx = tid & 63;         // staging px (slot spx+1)
    const int scg = tid >> 6;         // staging ci-group of 16 (0..3)

    __shared__ __align__(16) char ring[NRS * ROWB2];   // 50,688 B
    __shared__ float sEW[E_];

    // ---- gate (wave 0 recomputes; broadcast via LDS) ----
    if (tid < 64) {
        const float p = pooled[b * C_ + lane];
        float part[E_];
#pragma unroll
        for (int e = 0; e < E_; e++) part[e] = p * gw[e * C_ + lane];
#pragma unroll
        for (int off = 32; off; off >>= 1)
#pragma unroll
            for (int e = 0; e < E_; e++) part[e] += __shfl_down(part[e], off);
        if (lane == 0) {
            float lg[E_];
#pragma unroll
            for (int e = 0; e < E_; e++) lg[e] = part[e] + gb[e];
            float m = fmaxf(fmaxf(lg[0], lg[1]), fmaxf(lg[2], lg[3]));
            float ex[E_], sum = 0.f;
#pragma unroll
            for (int e = 0; e < E_; e++) { ex[e] = __expf(lg[e] - m); sum += ex[e]; }
            const float inv = 1.0f / sum;
            int i1 = 0;
            for (int e = 1; e < E_; e++) if (ex[e] > ex[i1]) i1 = e;
            int i2 = -1;
            for (int e = 0; e < E_; e++) {
                if (e == i1) continue;
                if (i2 < 0 || ex[e] > ex[i2]) i2 = e;
            }
#pragma unroll
            for (int e = 0; e < E_; e++)
                sEW[e] = (e == i1 || e == i2) ? ex[e] * inv : 0.f;
        }
    }
    __syncthreads();

    int e0 = 0, e1 = 0; float w0 = 0.f, w1 = 0.f;
    {
        int found = 0;
        for (int e = 0; e < E_; e++) {
            float we = sEW[e];
            if (we != 0.f) {
                if (!found) { e0 = e; w0 = we; found = 1; }
                else        { e1 = e; w1 = we; }
            }
        }
        if (w1 == 0.f) e1 = e0;   // degenerate: w1=0 zeroes its contribution
    }

    const float* cb0 = cb + e0 * C_;
    const float* cb1 = cb + e1 * C_;
    const float* kkp = kk + b * C_;

    float pv[2][16], ph[8];
    // STAGE(pr): stage rows pr, pr+1 (this thread: 16 ci x 1 px of each row)
    auto STAGE = [&](int pr) {
#pragma unroll
        for (int rr = 0; rr < 2; ++rr) {
            const int r = pr + rr;
            if ((unsigned)r < (unsigned)H_) {
                const float* src = in + ((size_t)(b * C_ + scg * 16) * H_ + r) * W_ + x0g + spx;
#pragma unroll
                for (int i = 0; i < 16; ++i) pv[rr][i] = src[(size_t)i * HW_];
            } else {
#pragma unroll
                for (int i = 0; i < 16; ++i) pv[rr][i] = 0.f;
            }
        }
        if (tid < 32) {
            const int hp = tid & 1;
            const int cgh = (tid >> 1) & 7;
            const int hrow = tid >> 4;           // 0/1
            const int rr = pr + hrow;
            const int pg = hp ? (x0g + 64) : (x0g - 1);
            const bool ok = ((unsigned)rr < (unsigned)H_) && ((unsigned)pg < (unsigned)W_);
            const float* src = in + ((size_t)(b * C_ + cgh * 8) * H_ + (((unsigned)rr < (unsigned)H_) ? rr : 0)) * W_ + (ok ? pg : 0);
#pragma unroll
            for (int i = 0; i < 8; ++i) ph[i] = ok ? src[(size_t)i * HW_] : 0.f;
        }
    };
    // COMMIT(sl0): row rr lands in slot (sl0+rr)%6
    auto COMMIT = [&](int sl0) {
#pragma unroll
        for (int rr = 0; rr < 2; ++rr) {
            int sl = sl0 + rr; if (sl >= NRS) sl -= NRS;
            bfrag8 f0, f1;
#pragma unroll
            for (int j = 0; j < 8; ++j) {
                f0[j] = (short)f2bf(pv[rr][j]);
                f1[j] = (short)f2bf(pv[rr][8 + j]);
            }
            char* bp = ring + sl * ROWB2 + (spx + 1) * 16;
            *(bfrag8*)(bp + (scg * 2) * PLANE2) = f0;
            *(bfrag8*)(bp + (scg * 2 + 1) * PLANE2) = f1;
        }
        if (tid < 32) {
            const int hp = tid & 1;
            const int cgh = (tid >> 1) & 7;
            const int hrow = tid >> 4;
            int slh = sl0 + hrow; if (slh >= NRS) slh -= NRS;
            bfrag8 g;
#pragma unroll
            for (int i = 0; i < 8; ++i) g[i] = (short)f2bf(ph[i]);
            *(bfrag8*)(ring + slh * ROWB2 + cgh * PLANE2 + (hp ? 65 : 0) * 16) = g;
        }
    };

    // prologue: rows h0-1..h0+2 -> locals 0..3  (local(r) = r - h0 + 1)
    STAGE(h0 - 1); COMMIT(0);
    STAGE(h0 + 1); COMMIT(2);
    __syncthreads();

    const char* wb0 = (const char*)wT2 + (size_t)e0 * 73728 + ch * 4096 + lane * 16;
    const char* wb1 = (const char*)wT2 + (size_t)e1 * 73728 + ch * 4096 + lane * 16;

    for (int t = 0; t < RG / 2; ++t) {
        if (t + 1 < RG / 2) STAGE(h0 + 2 * t + 3);   // rows +3,+4 in flight over MFMA

        const int myloc = 2 * t + rh;                // local of this wave's row

        f32x16 A00, A01, A10, A11;   // (e0,q0)(e0,q1)(e1,q0)(e1,q1): 32co x 32px each
#pragma unroll
        for (int i = 0; i < 16; ++i) { A00[i] = 0.f; A01[i] = 0.f; A10[i] = 0.f; A11[i] = 0.f; }

#pragma unroll 1
        for (int ky = 0; ky < 3; ++ky) {
            int u = myloc + ky; if (u >= NRS) u -= NRS;
            const char* rb = ring + u * ROWB2;
            const char* wk0 = wb0 + ky * 24576;
            const char* wk1 = wb1 + ky * 24576;
#pragma unroll 1
            for (int kx = 0; kx < 3; ++kx) {
#pragma unroll
                for (int kb = 0; kb < 4; ++kb) {
                    bfrag8 a0 = *(const bfrag8*)(wk0 + kx * 8192 + kb * 1024);
                    bfrag8 a1 = *(const bfrag8*)(wk1 + kx * 8192 + kb * 1024);
                    const char* bp = rb + (kb * 2 + lh) * PLANE2 + (ln + kx) * 16;
                    bfrag8 b0 = *(const bfrag8*)(bp);
                    bfrag8 b1 = *(const bfrag8*)(bp + 512);   // +32 slots
                    A00 = __builtin_amdgcn_mfma_f32_32x32x16_bf16(a0, b0, A00, 0, 0, 0);
                    A01 = __builtin_amdgcn_mfma_f32_32x32x16_bf16(a0, b1, A01, 0, 0, 0);
                    A10 = __builtin_amdgcn_mfma_f32_32x32x16_bf16(a1, b0, A10, 0, 0, 0);
                    A11 = __builtin_amdgcn_mfma_f32_32x32x16_bf16(a1, b1, A11, 0, 0, 0);
                }
            }
        }

        // commit rows h0+2t+3/+4 into locals (2t+4)%6,(2t+5)%6 (unread this step)
        if (t + 1 < RG / 2) {
            int sl0 = 2 * t + 4; if (sl0 >= NRS) sl0 -= NRS;
            COMMIT(sl0);
        }

        // epilogue: out = resid(bf16, local myloc+1) + relu(a+b)*k*w (both experts)
        const int row = h0 + 2 * t + rh;
        int v = myloc + 1; if (v >= NRS) v -= NRS;
        const char* rm1 = ring + v * ROWB2 + lh * 8;
        bfrag4 ra0[4], ra1[4];
#pragma unroll
        for (int c = 0; c < 4; ++c) {
            ra0[c] = *(const bfrag4*)(rm1 + (ch * 4 + c) * PLANE2 + (ln + 1) * 16);
            ra1[c] = *(const bfrag4*)(rm1 + (ch * 4 + c) * PLANE2 + (ln + 33) * 16);
        }
#pragma unroll
        for (int g = 0; g < 16; ++g) {
            const int r_ = g & 3, c_ = g >> 2;
            const int co = co0 + r_ + 8 * c_ + 4 * lh;
            const float kv = kkp[co];
            const float f0 = kv * w0, f1 = kv * w1;
            const float b0v = cb0[co], b1v = cb1[co];
            const size_t base = ((size_t)(b * C_ + co) * H_ + row) * W_ + x0g;
            out[base + ln]      = bf2f((unsigned short)ra0[c_][r_])
                                  + fmaxf(A00[g] + b0v, 0.f) * f0
                                  + fmaxf(A10[g] + b1v, 0.f) * f1;
            out[base + 32 + ln] = bf2f((unsigned short)ra1[c_][r_])
                                  + fmaxf(A01[g] + b0v, 0.f) * f0
                                  + fmaxf(A11[g] + b1v, 0.f) * f1;
        }

        __syncthreads();   // single barrier: commits visible; next step's overwrites safe
    }
}

// ================= fallback (fp32 path, used only if ws too small) =================
#define CHUNK 32

__global__ __launch_bounds__(256) void pool_kernel(const float* __restrict__ in,
                                                   float* __restrict__ pooled) {
    const int bc = blockIdx.x;
    const float* p = in + (size_t)bc * HW_;
    float s = 0.f;
    for (int i = threadIdx.x; i < HW_ / 4; i += 256) {
        float4 v = ((const float4*)p)[i];
        s += v.x + v.y + v.z + v.w;
    }
    for (int off = 32; off; off >>= 1) s += __shfl_down(s, off);
    __shared__ float red[4];
    const int lane = threadIdx.x & 63, wv = threadIdx.x >> 6;
    if (lane == 0) red[wv] = s;
    __syncthreads();
    if (threadIdx.x == 0)
        pooled[bc] = (red[0] + red[1] + red[2] + red[3]) * (1.0f / (float)HW_);
}

__global__ __launch_bounds__(256) void wtr_kernel(const float* __restrict__ cw,
                                                  float* __restrict__ wT) {
    const int idx = blockIdx.x * 256 + threadIdx.x;
    if (idx >= E_ * C_ * 9 * C_) return;
    const int co = idx & 63;
    const int t2 = idx >> 6;
    const int tap = t2 % 9;
    const int t3 = t2 / 9;
    const int ci = t3 & 63;
    const int e = t3 >> 6;
    wT[idx] = cw[(((e * C_ + co) * C_ + ci) * 9) + tap];
}

__global__ __launch_bounds__(512) void conv_fallback(const float* __restrict__ in,
                                                     const float* __restrict__ kk,
                                                     const float* __restrict__ wT,
                                                     const float* __restrict__ cb,
                                                     const float* __restrict__ ew,
                                                     float* __restrict__ out) {
    const int bid = blockIdx.x;
    const int b = bid / H_;
    const int h = bid % H_;
    const int tid = threadIdx.x;
    const int lane = tid & 63;
    const int wv = tid >> 6;
    const int x0 = wv * 16;

    __shared__ float sIn[CHUNK * 3 * W_];

    float w0 = 0.f, w1 = 0.f;
    int e0 = 0, e1 = 0;
    {
        float we[E_];
#pragma unroll
        for (int e = 0; e < E_; e++) we[e] = ew[b * E_ + e];
        int found = 0;
        for (int e = 0; e < E_; e++) {
            if (we[e] != 0.f) {
                if (!found) { e0 = e; w0 = we[e]; found = 1; }
                else        { e1 = e; w1 = we[e]; }
            }
        }
        if (w1 == 0.f) e1 = e0;
    }

    float acc0[16], acc1[16];
#pragma unroll
    for (int i = 0; i < 16; i++) { acc0[i] = 0.f; acc1[i] = 0.f; }

    for (int cblk = 0; cblk < C_ / CHUNK; cblk++) {
        const int cbase = cblk * CHUNK;
        __syncthreads();
        for (int f = tid; f < CHUNK * 3 * W_ / 4; f += 512) {
            const int fi = f * 4;
            const int ci = fi / (3 * W_);
            const int rem = fi - ci * 3 * W_;
            const int kyy = rem / W_;
            const int x = rem - kyy * W_;
            const int hh = h + kyy - 1;
            float4 v = make_float4(0.f, 0.f, 0.f, 0.f);
            if (hh >= 0 && hh < H_)
                v = *(const float4*)(in + ((size_t)(b * C_ + cbase + ci) * H_ + hh) * W_ + x);
            *(float4*)(sIn + fi) = v;
        }
        __syncthreads();

        const float* wp0 = wT + (size_t)((e0 * C_ + cbase) * 9) * C_ + lane;
        const float* wp1 = wT + (size_t)((e1 * C_ + cbase) * 9) * C_ + lane;
        for (int ci = 0; ci < CHUNK; ci++) {
            float wa[9], wb[9];
#pragma unroll
            for (int t = 0; t < 9; t++) {
                wa[t] = wp0[(ci * 9 + t) * C_];
                wb[t] = wp1[(ci * 9 + t) * C_];
            }
            const float* rowp = sIn + ci * 3 * W_;
#pragma unroll
            for (int kyy = 0; kyy < 3; kyy++) {
                float xin[18];
                const float* rp = rowp + kyy * W_ + x0;
                xin[0] = (x0 == 0) ? 0.f : rp[-1];
#pragma unroll
                for (int j = 0; j < 16; j += 4) {
                    float4 v = *(const float4*)(rp + j);
                    xin[1 + j] = v.x; xin[2 + j] = v.y; xin[3 + j] = v.z; xin[4 + j] = v.w;
                }
                xin[17] = (x0 + 16 >= W_) ? 0.f : rp[16];
                const int t0 = kyy * 3;
#pragma unroll
                for (int x = 0; x < 16; x++) {
                    acc0[x] += xin[x] * wa[t0] + xin[x + 1] * wa[t0 + 1] + xin[x + 2] * wa[t0 + 2];
                    acc1[x] += xin[x] * wb[t0] + xin[x + 1] * wb[t0 + 1] + xin[x + 2] * wb[t0 + 2];
                }
            }
        }
    }

    const float kv = kk[b * C_ + lane];
    const float b0v = cb[e0 * C_ + lane];
    const float b1v = cb[e1 * C_ + lane];
    const float kw0 = kv * w0, kw1 = kv * w1;
    const size_t obase = ((size_t)(b * C_ + lane) * H_ + h) * W_ + x0;
#pragma unroll
    for (int x = 0; x < 16; x += 4) {
        float4 iv = *(const float4*)(in + obase + x);
        float4 ov;
        ov.x = iv.x + fmaxf(acc0[x + 0] + b0v, 0.f) * kw0 + fmaxf(acc1[x + 0] + b1v, 0.f) * kw1;
        ov.y = iv.y + fmaxf(acc0[x + 1] + b0v, 0.f) * kw0 + fmaxf(acc1[x + 1] + b1v, 0.f) * kw1;
        ov.z = iv.z + fmaxf(acc0[x + 2] + b0v, 0.f) * kw0 + fmaxf(acc1[x + 2] + b1v, 0.f) * kw1;
        ov.w = iv.w + fmaxf(acc0[x + 3] + b0v, 0.f) * kw0 + fmaxf(acc1[x + 3] + b1v, 0.f) * kw1;
        *(float4*)(out + obase + x) = ov;
    }
}

extern "C" void kernel_launch(void* const* d_in, const int* in_sizes, int n_in,
                              void* d_out, int out_size, void* d_ws, size_t ws_size,
                              hipStream_t stream) {
    const float* inputs = (const float*)d_in[0];
    const float* k      = (const float*)d_in[1];
    const float* gate_w = (const float*)d_in[2];
    const float* gate_b = (const float*)d_in[3];
    const float* conv_w = (const float*)d_in[4];
    const float* conv_b = (const float*)d_in[5];
    float* out = (float*)d_out;
    char* wsb = (char*)d_ws;

    if (ws_size >= WS_NEEDED) {
        unsigned short* wT2 = (unsigned short*)wsb;
        float* pooled = (float*)(wsb + OFF_POOL);

        pool_wcvt<<<B_ * C_, 256, 0, stream>>>(inputs, conv_w, pooled, wT2);
        conv_4b<<<512, 256, 0, stream>>>(inputs, k, conv_b, pooled,
                                         gate_w, gate_b, wT2, out);
    } else {
        float* ws = (float*)d_ws;
        float* wTf    = ws + FB_WT_OFF;
        float* pooled = ws + FB_POOLED_OFF;
        float* ewbuf  = ws + FB_EW_OFF;

        pool_kernel<<<B_ * C_, 256, 0, stream>>>(inputs, pooled);
        gate_kernel<<<1, 64, 0, stream>>>(pooled, gate_w, gate_b, ewbuf);
        wtr_kernel<<<(E_ * C_ * 9 * C_ + 255) / 256, 256, 0, stream>>>(conv_w, wTf);
        conv_fallback<<<B_ * H_, 512, 0, stream>>>(inputs, k, wTf, conv_b, ewbuf, out);
    }
}

// Round 20
// 87.175 us; speedup vs baseline: 1.5669x; 1.0330x over previous
//
#include <hip/hip_runtime.h>

typedef __attribute__((ext_vector_type(8))) short bfrag8;    // 8 bf16 (4 VGPRs)
typedef __attribute__((ext_vector_type(4))) short bfrag4;    // 4 bf16 (2 VGPRs)
typedef __attribute__((ext_vector_type(16))) float f32x16;   // 32x32 MFMA acc

#define B_ 16
#define C_ 64
#define H_ 128
#define W_ 128
#define E_ 4
#define HW_ (H_ * W_)

// ring geometry: 64-px half-rows, 66 slots (px-1..64 rel), 8 ci-chunks of 8
#define NSL 66
#define PLANE2 (NSL * 16)       // 1056 B
#define ROWB2  (8 * PLANE2)     // 8448 B
#define RG 4                    // output rows per block (1024 blocks)
#define NRS 5                   // ring slots (2-deep pipeline)

// raw barrier: flush LDS writes only; KEEP global loads in flight
// (__syncthreads would emit s_waitcnt vmcnt(0) and kill the prefetch pipeline)
#define BARRIER() do { \
    asm volatile("s_waitcnt lgkmcnt(0)" ::: "memory"); \
    __builtin_amdgcn_s_barrier(); \
} while (0)

// ---- fast-path ws layout (bytes) ----
// wT2: bf16 MFMA A-fragment layout [e][tap][ch][kb][lane64][8]
#define WT_ELEMS (4 * 9 * 2 * 4 * 64 * 8)      // 147,456 bf16
#define OFF_POOL (WT_ELEMS * 2)
#define OFF_EW   (OFF_POOL + 1024 * 4)
#define WS_NEEDED ((size_t)(OFF_EW + 64 * 4))

// ---- fallback ws layout (floats) ----
#define FB_WT_OFF 0
#define FB_POOLED_OFF 147456
#define FB_EW_OFF 148480

__device__ inline unsigned short f2bf(float f) {
    unsigned u = __builtin_bit_cast(unsigned, f);
    unsigned r = u + 0x7FFFu + ((u >> 16) & 1u);
    return (unsigned short)(r >> 16);
}
__device__ inline float bf2f(unsigned short s) {
    return __builtin_bit_cast(float, (unsigned)s << 16);
}

// ---------------- pool (per (b,c) block) + fused weight convert to frag layout ----------------
__global__ __launch_bounds__(256) void pool_wcvt(const float* __restrict__ in,
                                                 const float* __restrict__ cw,
                                                 float* __restrict__ pooled,
                                                 unsigned short* __restrict__ wT2) {
    if (blockIdx.x < 576) {
        const int idx = blockIdx.x * 256 + threadIdx.x;   // 0..147455
        const int j = idx & 7;
        const int l = (idx >> 3) & 63;
        const int f = idx >> 9;          // frag 0..287 = ((e*9+tap)*2+ch)*4+kb
        const int kb = f & 3;
        const int chh = (f >> 2) & 1;
        const int et = f >> 3;
        const int tap = et % 9;
        const int e = et / 9;
        const int co = chh * 32 + (l & 31);
        const int ci = kb * 16 + (l >> 5) * 8 + j;
        wT2[idx] = f2bf(cw[(((e * C_ + co) * C_ + ci) * 9) + tap]);
    }
    const int bc = blockIdx.x;
    const float* p = in + (size_t)bc * HW_;
    float s = 0.f;
    for (int i = threadIdx.x; i < HW_ / 4; i += 256) {
        float4 v = ((const float4*)p)[i];
        s += v.x + v.y + v.z + v.w;
    }
    for (int off = 32; off; off >>= 1) s += __shfl_down(s, off);
    __shared__ float red[4];
    const int lane = threadIdx.x & 63, wv = threadIdx.x >> 6;
    if (lane == 0) red[wv] = s;
    __syncthreads();
    if (threadIdx.x == 0)
        pooled[bc] = (red[0] + red[1] + red[2] + red[3]) * (1.0f / (float)HW_);
}

// ---------------- gate (fallback path only; fast path folds gate into conv) ----------------
__global__ void gate_kernel(const float* __restrict__ pooled,
                            const float* __restrict__ gate_w,
                            const float* __restrict__ gate_b,
                            float* __restrict__ ew) {
    const int b = threadIdx.x;
    if (b >= B_) return;
    float lg[E_];
    for (int e = 0; e < E_; e++) {
        float s = gate_b[e];
        for (int c = 0; c < C_; c++) s += pooled[b * C_ + c] * gate_w[e * C_ + c];
        lg[e] = s;
    }
    float m = fmaxf(fmaxf(lg[0], lg[1]), fmaxf(lg[2], lg[3]));
    float ex[E_], sum = 0.f;
    for (int e = 0; e < E_; e++) { ex[e] = expf(lg[e] - m); sum += ex[e]; }
    for (int e = 0; e < E_; e++) ex[e] /= sum;
    int i1 = 0;
    for (int e = 1; e < E_; e++) if (ex[e] > ex[i1]) i1 = e;
    int i2 = -1;
    for (int e = 0; e < E_; e++) {
        if (e == i1) continue;
        if (i2 < 0 || ex[e] > ex[i2]) i2 = e;
    }
    for (int e = 0; e < E_; e++)
        ew[b * E_ + e] = (e == i1 || e == i2) ? ex[e] : 0.f;
}

// ---------------- conv: raw-barrier + 2-deep stage pipeline (5-slot ring) ----------------
// r16 chassis (1024 blocks = img x pxhalf x rowgroup(32); 4 waves = ch x pq;
// wave tile 32co x 32px x 2 experts) with the barrier-drain fix:
//  (a) raw s_barrier + lgkmcnt(0)-only flush -> global loads survive barriers;
//  (b) 5-slot ring, commit-at-step-top: row r's loads issue one FULL step
//      before their vmcnt wait (~1200 cyc > 900 cyc HBM latency).
// Schedule (slot(r) = (r-h0+1)%5), fully unrolled, static pvA/pvB buffers:
//  prologue: commit rows h0-1,h0,h0+1 -> slots 0,1,2; row h0+2 in flight (pvB)
//  step0: stage h0+3 (pvA) | commit pvB->slot3 | MFMA 0,1,2 | epi h0+0 | bar
//  step1: stage h0+4 (pvB) | commit pvA->slot4 | MFMA 1,2,3 | epi h0+1 | bar
//  step2:                    commit pvB->slot0 | MFMA 2,3,4 | epi h0+2 | bar
//  step3:                                        MFMA 3,4,0 | epi h0+3
__global__ __launch_bounds__(256, 1) void conv_pipe(const float* __restrict__ in,
                                                    const float* __restrict__ kk,
                                                    const float* __restrict__ cb,
                                                    const float* __restrict__ pooled,
                                                    const float* __restrict__ gw,
                                                    const float* __restrict__ gb,
                                                    const unsigned short* __restrict__ wT2,
                                                    float* __restrict__ out) {
    const int raw = blockIdx.x;                     // 1024 blocks
    const int swz = (raw & 7) * 128 + (raw >> 3);   // XCD-bijective (1024 % 8 == 0)
    const int b   = swz >> 6;                       // 64 blocks per image
    const int pxh = (swz >> 5) & 1;
    const int h0  = (swz & 31) * RG;
    const int x0g = pxh * 64;

    const int tid = threadIdx.x;
    const int lane = tid & 63;
    const int wv = tid >> 6;          // 0..3
    const int ln = lane & 31;
    const int lh = lane >> 5;
    const int ch = wv & 1;            // co half
    const int pq = wv >> 1;           // 32-px quarter within the 64-px half
    const int co0 = ch * 32;

    const int spx = tid & 63;         // staging px (slot spx+1)
    const int scg = tid >> 6;         // staging ci-group of 16

    __shared__ __align__(16) char ring[NRS * ROWB2];   // 42,240 B
    __shared__ float sEW[E_];

    // ---- gate (wave 0 recomputes; broadcast via LDS) ----
    if (tid < 64) {
        const float p = pooled[b * C_ + lane];
        float part[E_];
#pragma unroll
        for (int e = 0; e < E_; e++) part[e] = p * gw[e * C_ + lane];
#pragma unroll
        for (int off = 32; off; off >>= 1)
#pragma unroll
            for (int e = 0; e < E_; e++) part[e] += __shfl_down(part[e], off);
        if (lane == 0) {
            float lg[E_];
#pragma unroll
            for (int e = 0; e < E_; e++) lg[e] = part[e] + gb[e];
            float m = fmaxf(fmaxf(lg[0], lg[1]), fmaxf(lg[2], lg[3]));
            float ex[E_], sum = 0.f;
#pragma unroll
            for (int e = 0; e < E_; e++) { ex[e] = __expf(lg[e] - m); sum += ex[e]; }
            const float inv = 1.0f / sum;
            int i1 = 0;
            for (int e = 1; e < E_; e++) if (ex[e] > ex[i1]) i1 = e;
            int i2 = -1;
            for (int e = 0; e < E_; e++) {
                if (e == i1) continue;
                if (i2 < 0 || ex[e] > ex[i2]) i2 = e;
            }
#pragma unroll
            for (int e = 0; e < E_; e++)
                sEW[e] = (e == i1 || e == i2) ? ex[e] * inv : 0.f;
        }
    }
    __syncthreads();

    int e0 = 0, e1 = 0; float w0 = 0.f, w1 = 0.f;
    {
        int found = 0;
        for (int e = 0; e < E_; e++) {
            float we = sEW[e];
            if (we != 0.f) {
                if (!found) { e0 = e; w0 = we; found = 1; }
                else        { e1 = e; w1 = we; }
            }
        }
        if (w1 == 0.f) e1 = e0;   // degenerate: w1=0 zeroes its contribution
    }

    const float* cb0 = cb + e0 * C_;
    const float* cb1 = cb + e1 * C_;
    const float* kkp = kk + b * C_;

    float pvA[16], phA[8], pvB[16], phB[8];

    auto STAGEA = [&](int r) {
        if ((unsigned)r < (unsigned)H_) {
            const float* src = in + ((size_t)(b * C_ + scg * 16) * H_ + r) * W_ + x0g + spx;
#pragma unroll
            for (int i = 0; i < 16; ++i) pvA[i] = src[(size_t)i * HW_];
        } else {
#pragma unroll
            for (int i = 0; i < 16; ++i) pvA[i] = 0.f;
        }
        if (tid < 16) {
            const int hp = tid & 1, cgh = tid >> 1;
            const int pg = hp ? (x0g + 64) : (x0g - 1);
            const bool ok = ((unsigned)r < (unsigned)H_) && ((unsigned)pg < (unsigned)W_);
            const float* src = in + ((size_t)(b * C_ + cgh * 8) * H_ + (((unsigned)r < (unsigned)H_) ? r : 0)) * W_ + (ok ? pg : 0);
#pragma unroll
            for (int i = 0; i < 8; ++i) phA[i] = ok ? src[(size_t)i * HW_] : 0.f;
        }
    };
    auto STAGEB = [&](int r) {
        if ((unsigned)r < (unsigned)H_) {
            const float* src = in + ((size_t)(b * C_ + scg * 16) * H_ + r) * W_ + x0g + spx;
#pragma unroll
            for (int i = 0; i < 16; ++i) pvB[i] = src[(size_t)i * HW_];
        } else {
#pragma unroll
            for (int i = 0; i < 16; ++i) pvB[i] = 0.f;
        }
        if (tid < 16) {
            const int hp = tid & 1, cgh = tid >> 1;
            const int pg = hp ? (x0g + 64) : (x0g - 1);
            const bool ok = ((unsigned)r < (unsigned)H_) && ((unsigned)pg < (unsigned)W_);
            const float* src = in + ((size_t)(b * C_ + cgh * 8) * H_ + (((unsigned)r < (unsigned)H_) ? r : 0)) * W_ + (ok ? pg : 0);
#pragma unroll
            for (int i = 0; i < 8; ++i) phB[i] = ok ? src[(size_t)i * HW_] : 0.f;
        }
    };
    auto COMMITA = [&](int rs) {
        bfrag8 f0, f1;
#pragma unroll
        for (int j = 0; j < 8; ++j) {
            f0[j] = (short)f2bf(pvA[j]);
            f1[j] = (short)f2bf(pvA[8 + j]);
        }
        char* bp = ring + rs * ROWB2 + (spx + 1) * 16;
        *(bfrag8*)(bp + (scg * 2) * PLANE2) = f0;
        *(bfrag8*)(bp + (scg * 2 + 1) * PLANE2) = f1;
        if (tid < 16) {
            const int hp = tid & 1, cgh = tid >> 1;
            bfrag8 g;
#pragma unroll
            for (int i = 0; i < 8; ++i) g[i] = (short)f2bf(phA[i]);
            *(bfrag8*)(ring + rs * ROWB2 + cgh * PLANE2 + (hp ? 65 : 0) * 16) = g;
        }
    };
    auto COMMITB = [&](int rs) {
        bfrag8 f0, f1;
#pragma unroll
        for (int j = 0; j < 8; ++j) {
            f0[j] = (short)f2bf(pvB[j]);
            f1[j] = (short)f2bf(pvB[8 + j]);
        }
        char* bp = ring + rs * ROWB2 + (spx + 1) * 16;
        *(bfrag8*)(bp + (scg * 2) * PLANE2) = f0;
        *(bfrag8*)(bp + (scg * 2 + 1) * PLANE2) = f1;
        if (tid < 16) {
            const int hp = tid & 1, cgh = tid >> 1;
            bfrag8 g;
#pragma unroll
            for (int i = 0; i < 8; ++i) g[i] = (short)f2bf(phB[i]);
            *(bfrag8*)(ring + rs * ROWB2 + cgh * PLANE2 + (hp ? 65 : 0) * 16) = g;
        }
    };

    const char* wb0 = (const char*)wT2 + (size_t)e0 * 73728 + ch * 4096 + lane * 16;
    const char* wb1 = (const char*)wT2 + (size_t)e1 * 73728 + ch * 4096 + lane * 16;

    // DO_STEP: MFMA over slots (s0, s0+1, s0+2)%5, epilogue for `row`
    auto DO_STEP = [&](int s0, int row) {
        f32x16 Ae0, Ae1;
#pragma unroll
        for (int i = 0; i < 16; ++i) { Ae0[i] = 0.f; Ae1[i] = 0.f; }
#pragma unroll 1
        for (int ky = 0; ky < 3; ++ky) {
            int u = s0 + ky; if (u >= NRS) u -= NRS;
            const char* rb = ring + u * ROWB2;
            const char* wk0 = wb0 + ky * 24576;
            const char* wk1 = wb1 + ky * 24576;
#pragma unroll 1
            for (int kx = 0; kx < 3; ++kx) {
#pragma unroll
                for (int kb = 0; kb < 4; ++kb) {
                    bfrag8 a0 = *(const bfrag8*)(wk0 + kx * 8192 + kb * 1024);
                    bfrag8 a1 = *(const bfrag8*)(wk1 + kx * 8192 + kb * 1024);
                    bfrag8 bb = *(const bfrag8*)(rb + (kb * 2 + lh) * PLANE2
                                                 + (pq * 32 + ln + kx) * 16);
                    Ae0 = __builtin_amdgcn_mfma_f32_32x32x16_bf16(a0, bb, Ae0, 0, 0, 0);
                    Ae1 = __builtin_amdgcn_mfma_f32_32x32x16_bf16(a1, bb, Ae1, 0, 0, 0);
                }
            }
        }
        int v = s0 + 1; if (v >= NRS) v -= NRS;
        const char* rm1 = ring + v * ROWB2 + (pq * 32 + ln + 1) * 16 + lh * 8;
        bfrag4 ra[4];
#pragma unroll
        for (int c = 0; c < 4; ++c)
            ra[c] = *(const bfrag4*)(rm1 + (ch * 4 + c) * PLANE2);
#pragma unroll
        for (int g = 0; g < 16; ++g) {
            const int r_ = g & 3, c_ = g >> 2;
            const int co = co0 + r_ + 8 * c_ + 4 * lh;
            const float kv = kkp[co];
            const size_t oi = ((size_t)(b * C_ + co) * H_ + row) * W_ + x0g + pq * 32 + ln;
            out[oi] = bf2f((unsigned short)ra[c_][r_])
                      + fmaxf(Ae0[g] + cb0[co], 0.f) * (kv * w0)
                      + fmaxf(Ae1[g] + cb1[co], 0.f) * (kv * w1);
        }
    };

    // ---- prologue: rows h0-1, h0, h0+1 -> slots 0,1,2; row h0+2 in flight (pvB)
    STAGEA(h0 - 1);
    STAGEB(h0);
    COMMITA(0);
    STAGEA(h0 + 1);
    COMMITB(1);
    STAGEB(h0 + 2);
    COMMITA(2);
    BARRIER();

    // ---- step 0
    STAGEA(h0 + 3);          // loads in flight across the whole step
    COMMITB(3);              // row h0+2 (staged in prologue: full-step latency)
    DO_STEP(0, h0 + 0);
    BARRIER();
    // ---- step 1
    STAGEB(h0 + 4);
    COMMITA(4);              // row h0+3
    DO_STEP(1, h0 + 1);
    BARRIER();
    // ---- step 2
    COMMITB(0);              // row h0+4
    DO_STEP(2, h0 + 2);
    BARRIER();
    // ---- step 3
    DO_STEP(3, h0 + 3);
}

// ================= fallback (fp32 path, used only if ws too small) =================
#define CHUNK 32

__global__ __launch_bounds__(256) void pool_kernel(const float* __restrict__ in,
                                                   float* __restrict__ pooled) {
    const int bc = blockIdx.x;
    const float* p = in + (size_t)bc * HW_;
    float s = 0.f;
    for (int i = threadIdx.x; i < HW_ / 4; i += 256) {
        float4 v = ((const float4*)p)[i];
        s += v.x + v.y + v.z + v.w;
    }
    for (int off = 32; off; off >>= 1) s += __shfl_down(s, off);
    __shared__ float red[4];
    const int lane = threadIdx.x & 63, wv = threadIdx.x >> 6;
    if (lane == 0) red[wv] = s;
    __syncthreads();
    if (threadIdx.x == 0)
        pooled[bc] = (red[0] + red[1] + red[2] + red[3]) * (1.0f / (float)HW_);
}

__global__ __launch_bounds__(256) void wtr_kernel(const float* __restrict__ cw,
                                                  float* __restrict__ wT) {
    const int idx = blockIdx.x * 256 + threadIdx.x;
    if (idx >= E_ * C_ * 9 * C_) return;
    const int co = idx & 63;
    const int t2 = idx >> 6;
    const int tap = t2 % 9;
    const int t3 = t2 / 9;
    const int ci = t3 & 63;
    const int e = t3 >> 6;
    wT[idx] = cw[(((e * C_ + co) * C_ + ci) * 9) + tap];
}

__global__ __launch_bounds__(512) void conv_fallback(const float* __restrict__ in,
                                                     const float* __restrict__ kk,
                                                     const float* __restrict__ wT,
                                                     const float* __restrict__ cb,
                                                     const float* __restrict__ ew,
                                                     float* __restrict__ out) {
    const int bid = blockIdx.x;
    const int b = bid / H_;
    const int h = bid % H_;
    const int tid = threadIdx.x;
    const int lane = tid & 63;
    const int wv = tid >> 6;
    const int x0 = wv * 16;

    __shared__ float sIn[CHUNK * 3 * W_];

    float w0 = 0.f, w1 = 0.f;
    int e0 = 0, e1 = 0;
    {
        float we[E_];
#pragma unroll
        for (int e = 0; e < E_; e++) we[e] = ew[b * E_ + e];
        int found = 0;
        for (int e = 0; e < E_; e++) {
            if (we[e] != 0.f) {
                if (!found) { e0 = e; w0 = we[e]; found = 1; }
                else        { e1 = e; w1 = we[e]; }
            }
        }
        if (w1 == 0.f) e1 = e0;
    }

    float acc0[16], acc1[16];
#pragma unroll
    for (int i = 0; i < 16; i++) { acc0[i] = 0.f; acc1[i] = 0.f; }

    for (int cblk = 0; cblk < C_ / CHUNK; cblk++) {
        const int cbase = cblk * CHUNK;
        __syncthreads();
        for (int f = tid; f < CHUNK * 3 * W_ / 4; f += 512) {
            const int fi = f * 4;
            const int ci = fi / (3 * W_);
            const int rem = fi - ci * 3 * W_;
            const int kyy = rem / W_;
            const int x = rem - kyy * W_;
            const int hh = h + kyy - 1;
            float4 v = make_float4(0.f, 0.f, 0.f, 0.f);
            if (hh >= 0 && hh < H_)
                v = *(const float4*)(in + ((size_t)(b * C_ + cbase + ci) * H_ + hh) * W_ + x);
            *(float4*)(sIn + fi) = v;
        }
        __syncthreads();

        const float* wp0 = wT + (size_t)((e0 * C_ + cbase) * 9) * C_ + lane;
        const float* wp1 = wT + (size_t)((e1 * C_ + cbase) * 9) * C_ + lane;
        for (int ci = 0; ci < CHUNK; ci++) {
            float wa[9], wb[9];
#pragma unroll
            for (int t = 0; t < 9; t++) {
                wa[t] = wp0[(ci * 9 + t) * C_];
                wb[t] = wp1[(ci * 9 + t) * C_];
            }
            const float* rowp = sIn + ci * 3 * W_;
#pragma unroll
            for (int kyy = 0; kyy < 3; kyy++) {
                float xin[18];
                const float* rp = rowp + kyy * W_ + x0;
                xin[0] = (x0 == 0) ? 0.f : rp[-1];
#pragma unroll
                for (int j = 0; j < 16; j += 4) {
                    float4 v = *(const float4*)(rp + j);
                    xin[1 + j] = v.x; xin[2 + j] = v.y; xin[3 + j] = v.z; xin[4 + j] = v.w;
                }
                xin[17] = (x0 + 16 >= W_) ? 0.f : rp[16];
                const int t0 = kyy * 3;
#pragma unroll
                for (int x = 0; x < 16; x++) {
                    acc0[x] += xin[x] * wa[t0] + xin[x + 1] * wa[t0 + 1] + xin[x + 2] * wa[t0 + 2];
                    acc1[x] += xin[x] * wb[t0] + xin[x + 1] * wb[t0 + 1] + xin[x + 2] * wb[t0 + 2];
                }
            }
        }
    }

    const float kv = kk[b * C_ + lane];
    const float b0v = cb[e0 * C_ + lane];
    const float b1v = cb[e1 * C_ + lane];
    const float kw0 = kv * w0, kw1 = kv * w1;
    const size_t obase = ((size_t)(b * C_ + lane) * H_ + h) * W_ + x0;
#pragma unroll
    for (int x = 0; x < 16; x += 4) {
        float4 iv = *(const float4*)(in + obase + x);
        float4 ov;
        ov.x = iv.x + fmaxf(acc0[x + 0] + b0v, 0.f) * kw0 + fmaxf(acc1[x + 0] + b1v, 0.f) * kw1;
        ov.y = iv.y + fmaxf(acc0[x + 1] + b0v, 0.f) * kw0 + fmaxf(acc1[x + 1] + b1v, 0.f) * kw1;
        ov.z = iv.z + fmaxf(acc0[x + 2] + b0v, 0.f) * kw0 + fmaxf(acc1[x + 2] + b1v, 0.f) * kw1;
        ov.w = iv.w + fmaxf(acc0[x + 3] + b0v, 0.f) * kw0 + fmaxf(acc1[x + 3] + b1v, 0.f) * kw1;
        *(float4*)(out + obase + x) = ov;
    }
}

extern "C" void kernel_launch(void* const* d_in, const int* in_sizes, int n_in,
                              void* d_out, int out_size, void* d_ws, size_t ws_size,
                              hipStream_t stream) {
    const float* inputs = (const float*)d_in[0];
    const float* k      = (const float*)d_in[1];
    const float* gate_w = (const float*)d_in[2];
    const float* gate_b = (const float*)d_in[3];
    const float* conv_w = (const float*)d_in[4];
    const float* conv_b = (const float*)d_in[5];
    float* out = (float*)d_out;
    char* wsb = (char*)d_ws;

    if (ws_size >= WS_NEEDED) {
        unsigned short* wT2 = (unsigned short*)wsb;
        float* pooled = (float*)(wsb + OFF_POOL);

        pool_wcvt<<<B_ * C_, 256, 0, stream>>>(inputs, conv_w, pooled, wT2);
        conv_pipe<<<1024, 256, 0, stream>>>(inputs, k, conv_b, pooled,
                                            gate_w, gate_b, wT2, out);
    } else {
        float* ws = (float*)d_ws;
        float* wTf    = ws + FB_WT_OFF;
        float* pooled = ws + FB_POOLED_OFF;
        float* ewbuf  = ws + FB_EW_OFF;

        pool_kernel<<<B_ * C_, 256, 0, stream>>>(inputs, pooled);
        gate_kernel<<<1, 64, 0, stream>>>(pooled, gate_w, gate_b, ewbuf);
        wtr_kernel<<<(E_ * C_ * 9 * C_ + 255) / 256, 256, 0, stream>>>(conv_w, wTf);
        conv_fallback<<<B_ * H_, 512, 0, stream>>>(inputs, k, wTf, conv_b, ewbuf, out);
    }
}